// Round 7
// baseline (2330.052 us; speedup 1.0000x reference)
//
#include <hip/hip_runtime.h>
#include <stdint.h>

// SymmetricContraction (MACE) on MI355X, fp32 I/O.
// R7: symmetric-table algebra (verified in R6: absmax 0.03125) with the
// register-pressure catastrophe fixed. R6 spilled x[4][16]+hoisted table
// loads to scratch (4.2 GB HBM traffic). R7: NT=2 nodes/lane (x[2][16]=32
// VGPRs), 4 waves (wave=mhat) x 2 passes cover 256 slots; x staged in LDS
// as float4-per-q (conflict-free b128); table read from global via
// wave-uniform addresses (19.2 KB/block, L1/L2-resident).
//   out[mhat] = sum_c x_c ( T1[c] + sum_{b<=c} x_b ( T2[cb]
//               + sum_{a<=b} T3[cb][a] x_a ) )

#define BN 2048
#define CN 128
#define EN 10

constexpr int LPAD(int b) { return 4 * (b / 4 + 1); }
constexpr int rowStart(int c, int b) {
    int s = 0;
    for (int cc = 0; cc < c; ++cc)
        for (int bb = 0; bb <= cc; ++bb) s += LPAD(bb);
    for (int bb = 0; bb < b; ++bb) s += LPAD(bb);
    return s;
}
constexpr int TP3 = rowStart(15, 15) + LPAD(15);   // 1040
static_assert(TP3 == 1040, "pad math");
#define ROWLEN 1200
#define T2OFF 1040
#define T1OFF 1176

// float offsets in ws
#define OFF_SRC 4096
#define OFF_TAB (OFF_SRC + 4 * ROWLEN * 36)
#define OFF_OUT (OFF_TAB + EN * CN * 4 * ROWLEN)
// end ~= 29.5 MB

// ints: wsI[0..9]=counts, wsI[16..25]=starts, wsI[32..]=plist
__global__ void compact_kernel(const float* __restrict__ yg, int* __restrict__ wsI) {
    const int e = blockIdx.x;          // one block per element
    const int tid = threadIdx.x;
    __shared__ int cnts[EN];
    __shared__ int cur;
    if (tid < EN) cnts[tid] = 0;
    if (tid == 0) cur = 0;
    __syncthreads();
    for (int b = tid; b < BN; b += 256) {
        const float* yr = yg + (size_t)b * EN;
#pragma unroll
        for (int ee = 0; ee < EN; ++ee)
            if (yr[ee] > 0.5f) { atomicAdd(&cnts[ee], 1); break; }
    }
    __syncthreads();
    int start = 0;
    for (int ee = 0; ee < e; ++ee) start += cnts[ee];
    if (tid == 0) { wsI[e] = cnts[e]; wsI[16 + e] = start; }
    for (int b = tid; b < BN; b += 256) {
        if (yg[(size_t)b * EN + e] > 0.5f) {
            int p = atomicAdd(&cur, 1);
            wsI[32 + start + p] = b;
        }
    }
}

// ---- symU: SRC[mhat][r<1200][k<36] (zero-padded). Verified in R6.
__global__ void symU_kernel(
    const float* __restrict__ U3_0, const float* __restrict__ U2_0,
    const float* __restrict__ U1_0, const float* __restrict__ U3_1,
    const float* __restrict__ U2_1, const float* __restrict__ U1_1,
    float* __restrict__ fw)
{
    const int r = blockIdx.x;
    const int mhat = blockIdx.y;
    const int k = threadIdx.x;
    if (k >= 36) return;
    const int m = (mhat == 0) ? 0 : (mhat - 1);
    const int K3 = (mhat == 0) ? 23 : 33;
    const int K2 = (mhat == 0) ? 4 : 5;
    const float* U3 = (mhat == 0) ? U3_0 : U3_1;
    const float* U2 = (mhat == 0) ? U2_0 : U2_1;
    const float* U1 = (mhat == 0) ? U1_0 : U1_1;
    float v = 0.f;
    if (r < TP3) {
        int cc = -1, bb = -1, off = 0, acc0 = 0;
        for (int c_ = 0; c_ < 16; ++c_)
            for (int b_ = 0; b_ <= c_; ++b_) {
                const int L = LPAD(b_);
                if (r >= acc0 && r < acc0 + L) { cc = c_; bb = b_; off = r - acc0; }
                acc0 += L;
            }
        if (off <= bb && k < K3) {
            const int a_ = off, b_ = bb, c_ = cc;
            int P[6][3] = {{a_, b_, c_}, {a_, c_, b_}, {b_, a_, c_},
                           {b_, c_, a_}, {c_, a_, b_}, {c_, b_, a_}};
            for (int p = 0; p < 6; ++p) {
                bool dup = false;
                for (int q = 0; q < p; ++q)
                    dup |= (P[q][0] == P[p][0] && P[q][1] == P[p][1] && P[q][2] == P[p][2]);
                if (!dup)
                    v += U3[(size_t)(((m * 16 + P[p][0]) * 16 + P[p][1]) * 16 + P[p][2]) * K3 + k];
            }
        }
    } else if (r < TP3 + 136) {
        const int p = r - TP3;
        int c_ = 0;
        while ((c_ + 1) * (c_ + 2) / 2 <= p) ++c_;
        const int b_ = p - c_ * (c_ + 1) / 2;
        if (k < K2) {
            v = U2[(size_t)((m * 16 + b_) * 16 + c_) * K2 + k];
            if (b_ != c_) v += U2[(size_t)((m * 16 + c_) * 16 + b_) * K2 + k];
        }
    } else if (r < TP3 + 136 + 16) {
        const int c_ = r - (TP3 + 136);
        if (k == 0) v = U1[m * 16 + c_];
    }
    fw[OFF_SRC + ((size_t)mhat * ROWLEN + r) * 36 + k] = v;
}

// ---- tabbuild: grid (15 tiles, 4 mhat, 10 e), 128 thr (chan), 5 groups.
__global__ __launch_bounds__(128) void tabbuild_kernel(
    const float* __restrict__ W3_0, const float* __restrict__ W2_0,
    const float* __restrict__ W1_0, const float* __restrict__ W3_1,
    const float* __restrict__ W2_1, const float* __restrict__ W1_1,
    float* __restrict__ fw)
{
    const int tile = blockIdx.x;   // 0..14, 80 rows each
    const int mhat = blockIdx.y;
    const int e = blockIdx.z;
    const int chan = threadIdx.x;
    const int K3 = (mhat == 0) ? 23 : 33;
    const int K2 = (mhat == 0) ? 4 : 5;
    const float* W3 = (mhat == 0) ? W3_0 : W3_1;
    const float* W2 = (mhat == 0) ? W2_0 : W2_1;
    const float* W1 = (mhat == 0) ? W1_0 : W1_1;

    float w3[33], w2[5];
#pragma unroll
    for (int k = 0; k < 33; ++k) w3[k] = (k < K3) ? W3[(e * K3 + k) * CN + chan] : 0.f;
#pragma unroll
    for (int k = 0; k < 5; ++k) w2[k] = (k < K2) ? W2[(e * K2 + k) * CN + chan] : 0.f;
    const float w1 = W1[e * CN + chan];

    const float* SRC = fw + OFF_SRC + (size_t)mhat * ROWLEN * 36;
    float* tabO = fw + OFF_TAB;
    __shared__ float trans[128 * 17];

    for (int g = 0; g < 5; ++g) {
        const int r0 = tile * 80 + g * 16;
        float res[16];
#pragma unroll
        for (int rr = 0; rr < 16; ++rr) {
            const int r = r0 + rr;
            const float* row = SRC + (size_t)r * 36;
            float acc = 0.f;
            if (r < TP3) {
#pragma unroll
                for (int k = 0; k < 33; ++k) acc = fmaf(row[k], w3[k], acc);
            } else if (r < T1OFF) {
#pragma unroll
                for (int k = 0; k < 5; ++k) acc = fmaf(row[k], w2[k], acc);
            } else if (r < T1OFF + 16) {
                acc = row[0] * w1;
            }
            res[rr] = acc;
        }
#pragma unroll
        for (int rr = 0; rr < 16; ++rr) trans[chan * 17 + rr] = res[rr];
        __syncthreads();
#pragma unroll
        for (int s = 0; s < 4; ++s) {
            const int cc = s * 32 + (chan >> 2);
            const int q = chan & 3;
            float4 v = make_float4(trans[cc * 17 + q * 4], trans[cc * 17 + q * 4 + 1],
                                   trans[cc * 17 + q * 4 + 2], trans[cc * 17 + q * 4 + 3]);
            *(float4*)(tabO + (size_t)(e * CN + cc) * (4 * ROWLEN) +
                       (size_t)mhat * ROWLEN + r0 + q * 4) = v;
        }
        __syncthreads();
    }
}

// ---- sc_main: block (chan, e); wave = mhat; NT=2, 2 passes per 256-sweep.
__global__ __launch_bounds__(256, 4) void sc_main(
    const float* __restrict__ xg, const float* __restrict__ fw,
    const int* __restrict__ wsI)
{
    const int chan = blockIdx.x;
    const int e = blockIdx.y;
    const int tid = threadIdx.x;
    const int lane = tid & 63;
    const int wave = tid >> 6;   // = mhat

    const float* T = fw + OFF_TAB + (size_t)(e * CN + chan) * (4 * ROWLEN) +
                     (size_t)wave * ROWLEN;   // wave-uniform
    __shared__ float4 xs4[4 * 256];           // [q][slot], 16 KB

    const int cnt = wsI[e];
    const int start = wsI[16 + e];
    const int* list = wsI + 32 + start;
    float* outws = (float*)(fw + OFF_OUT);
    const int col = (wave == 0) ? chan : (CN + chan * 3 + (wave - 1));

    for (int base = 0; base < cnt; base += 256) {
        {   // stage up to 256 nodes' x, float4-per-q
            const int slot = base + tid;
            const int n = (slot < cnt) ? list[slot] : list[cnt - 1];
            const float4* xp = (const float4*)(xg + ((size_t)n * CN + chan) * 16);
#pragma unroll
            for (int q = 0; q < 4; ++q) xs4[q * 256 + tid] = xp[q];
        }
        __syncthreads();

        const int rem = cnt - base;
        const int npass = ((rem < 256 ? rem : 256) + 127) >> 7;   // 1 or 2
        for (int pass = 0; pass < npass; ++pass) {
            const int sl = pass * 128 + lane;
            float x[2][16];
#pragma unroll
            for (int t = 0; t < 2; ++t) {
#pragma unroll
                for (int q = 0; q < 4; ++q) {
                    const float4 v = xs4[q * 256 + sl + t * 64];
                    x[t][q * 4 + 0] = v.x;
                    x[t][q * 4 + 1] = v.y;
                    x[t][q * 4 + 2] = v.z;
                    x[t][q * 4 + 3] = v.w;
                }
            }
            float acc0 = 0.f, acc1 = 0.f;
#pragma unroll
            for (int c = 0; c < 16; ++c) {
                const float g0 = T[T1OFF + c];
                float G0 = g0, G1 = g0;
#pragma unroll
                for (int b = 0; b <= c; ++b) {
                    const float hh = T[T2OFF + c * (c + 1) / 2 + b];
                    float H0 = hh, H1 = hh;
#pragma unroll
                    for (int q = 0; q <= b / 4; ++q) {
                        const float4 r = *(const float4*)(T + rowStart(c, b) + q * 4);
                        H0 = fmaf(r.x, x[0][q * 4 + 0], H0);
                        H1 = fmaf(r.x, x[1][q * 4 + 0], H1);
                        H0 = fmaf(r.y, x[0][q * 4 + 1], H0);
                        H1 = fmaf(r.y, x[1][q * 4 + 1], H1);
                        H0 = fmaf(r.z, x[0][q * 4 + 2], H0);
                        H1 = fmaf(r.z, x[1][q * 4 + 2], H1);
                        H0 = fmaf(r.w, x[0][q * 4 + 3], H0);
                        H1 = fmaf(r.w, x[1][q * 4 + 3], H1);
                    }
                    G0 = fmaf(x[0][b], H0, G0);
                    G1 = fmaf(x[1][b], H1, G1);
                }
                acc0 = fmaf(x[0][c], G0, acc0);
                acc1 = fmaf(x[1][c], G1, acc1);
            }
            const int s0 = base + pass * 128 + lane;
            if (s0 < cnt) outws[(size_t)col * BN + start + s0] = acc0;
            if (s0 + 64 < cnt) outws[(size_t)col * BN + start + s0 + 64] = acc1;
        }
        __syncthreads();
    }
}

// ---- finalize: outws[col][p] -> out[b][col]; grid (32 p-tiles, 4 c-chunks).
__global__ __launch_bounds__(256) void finalize(
    const float* __restrict__ fw, const int* __restrict__ wsI,
    float* __restrict__ outg)
{
    const int p0 = blockIdx.x * 64;
    const int c0 = blockIdx.y * 128;
    const int tid = threadIdx.x;
    __shared__ float buf[64 * 129];
    const float* outws = fw + OFF_OUT;
    for (int idx = tid; idx < 64 * 128; idx += 256) {
        const int pp = idx & 63, cc = idx >> 6;
        buf[pp * 129 + cc] = outws[(size_t)(c0 + cc) * BN + p0 + pp];
    }
    __syncthreads();
    for (int idx = tid; idx < 64 * 128; idx += 256) {
        const int cc = idx & 127, pp = idx >> 7;
        outg[(size_t)wsI[32 + p0 + pp] * 512 + c0 + cc] = buf[pp * 129 + cc];
    }
}

extern "C" void kernel_launch(void* const* d_in, const int* in_sizes, int n_in,
                              void* d_out, int out_size, void* d_ws, size_t ws_size,
                              hipStream_t stream) {
    const float* x = (const float*)d_in[0];
    const float* y = (const float*)d_in[1];
    const float* U3_0 = (const float*)d_in[2];
    const float* U2_0 = (const float*)d_in[3];
    const float* U1_0 = (const float*)d_in[4];
    const float* W3_0 = (const float*)d_in[5];
    const float* W2_0 = (const float*)d_in[6];
    const float* W1_0 = (const float*)d_in[7];
    const float* U3_1 = (const float*)d_in[8];
    const float* U2_1 = (const float*)d_in[9];
    const float* U1_1 = (const float*)d_in[10];
    const float* W3_1 = (const float*)d_in[11];
    const float* W2_1 = (const float*)d_in[12];
    const float* W1_1 = (const float*)d_in[13];
    float* out = (float*)d_out;
    float* fw = (float*)d_ws;
    int* wsI = (int*)d_ws;

    compact_kernel<<<EN, 256, 0, stream>>>(y, wsI);
    symU_kernel<<<dim3(ROWLEN, 4), 64, 0, stream>>>(U3_0, U2_0, U1_0, U3_1, U2_1, U1_1, fw);
    tabbuild_kernel<<<dim3(15, 4, EN), 128, 0, stream>>>(W3_0, W2_0, W1_0, W3_1, W2_1, W1_1, fw);
    sc_main<<<dim3(CN, EN), 256, 0, stream>>>(x, fw, wsI);
    finalize<<<dim3(32, 4), 256, 0, stream>>>(fw, wsI, out);
}